// Round 2
// baseline (1054.508 us; speedup 1.0000x reference)
//
#include <hip/hip_runtime.h>

// TeamMovementModel: 1472 LSTM sequences (1408 player + 64 ball), T=128, H=128, D=2,
// then FC (40 x 256) on [player_h ; ball_h].
//
// R2: 1024-thread blocks. Thread t -> gate row r = t>>1, k-half = (t&1)*64.
// 64 weight floats per thread held in VGPRs (asm keep-alive prevents the
// allocator from rematerializing the loads inside the step loop, which is
// what killed R1: VGPR_Count=80 < 128 needed -> W re-read from L2 every step).
// Lane pairs (2m, 2m+1) are in the same wave -> partial combine via
// __shfl_xor(.,1), no extra barrier. 2 barriers per step.

#define HDIM 128
#define TSTEPS 128
#define NPLAYER 1408   // 64*22
#define NSEQ 1472      // + 64 ball

__device__ __forceinline__ float rcp_fast(float x) { return __builtin_amdgcn_rcpf(x); }
__device__ __forceinline__ float sigmoid_f(float x) {
    return rcp_fast(1.0f + __expf(-x));
}
__device__ __forceinline__ float tanh_f(float x) {
    // tanh(x) = 1 - 2/(e^{2x}+1); stable at both extremes (rcp(inf)=0)
    return 1.0f - 2.0f * rcp_fast(__expf(2.0f * x) + 1.0f);
}

__global__ void __launch_bounds__(1024, 4)
lstm_kernel(const float* __restrict__ x_players, const float* __restrict__ x_ball,
            const float* __restrict__ p_w_ih, const float* __restrict__ p_w_hh,
            const float* __restrict__ p_b_ih, const float* __restrict__ p_b_hh,
            const float* __restrict__ b_w_ih, const float* __restrict__ b_w_hh,
            const float* __restrict__ b_b_ih, const float* __restrict__ b_b_hh,
            float* __restrict__ h_all)
{
    const int seq  = blockIdx.x;          // 0..1471
    const int t    = threadIdx.x;         // 0..1023
    const int r    = t >> 1;              // gate row 0..511  (i,f,g,o each 128 rows)
    const int half = t & 1;               // k-half: 0 -> [0,64), 1 -> [64,128)
    const bool ball = (seq >= NPLAYER);

    const float* w_ih = ball ? b_w_ih : p_w_ih;
    const float* w_hh = ball ? b_w_hh : p_w_hh;
    const float* bih  = ball ? b_b_ih : p_b_ih;
    const float* bhh  = ball ? b_b_hh : p_b_hh;
    const float* x    = ball ? (x_ball    + (size_t)(seq - NPLAYER) * TSTEPS * 2)
                             : (x_players + (size_t)seq * TSTEPS * 2);

    __shared__ __align__(16) float h_sh[HDIM];
    __shared__ __align__(16) float x_sh[TSTEPS * 2];
    __shared__ float gates_sh[4 * HDIM];

    if (t < TSTEPS * 2) x_sh[t] = x[t];
    if (t < HDIM) h_sh[t] = 0.0f;

    // 64 weight floats of row r, k-half `half` -> registers
    float w[64];
    {
        const float* wrow = w_hh + (size_t)r * HDIM + half * 64;
        #pragma unroll
        for (int k = 0; k < 64; k += 4) {
            float4 v = *(const float4*)(wrow + k);
            w[k] = v.x; w[k + 1] = v.y; w[k + 2] = v.z; w[k + 3] = v.w;
        }
        // keep-alive: make each weight value opaque so the allocator cannot
        // rematerialize the global loads inside the step loop (R1 failure mode)
        #pragma unroll
        for (int k = 0; k < 64; ++k) asm volatile("" : "+v"(w[k]));
    }
    // only the even (half==0) thread applies bias/x and the activation
    const float wi0  = w_ih[r * 2 + 0];
    const float wi1  = w_ih[r * 2 + 1];
    const float bias = bih[r] + bhh[r];
    float c = 0.0f;                       // cell state, owned by threads 0..127
    const bool is_g_gate = (r >= 2 * HDIM / 1 / 2 * 1, r >= 256) && (r < 384); // rows [256,384): tanh
    const float* hbase = h_sh + half * 64;

    __syncthreads();

    for (int step = 0; step < TSTEPS; ++step) {
        float a0 = 0.0f, a1 = 0.0f, a2 = 0.0f, a3 = 0.0f;
        #pragma unroll
        for (int k = 0; k < 64; k += 4) {
            float4 hv = *(const float4*)(hbase + k);   // 2-addr broadcast read (free)
            a0 = __builtin_fmaf(w[k],     hv.x, a0);
            a1 = __builtin_fmaf(w[k + 1], hv.y, a1);
            a2 = __builtin_fmaf(w[k + 2], hv.z, a2);
            a3 = __builtin_fmaf(w[k + 3], hv.w, a3);
        }
        float s = (a0 + a1) + (a2 + a3);
        s += __shfl_xor(s, 1);                         // combine the two k-halves
        if (half == 0) {
            const float x0 = x_sh[2 * step];
            const float x1 = x_sh[2 * step + 1];
            float g = s + __builtin_fmaf(wi1, x1, __builtin_fmaf(wi0, x0, bias));
            // rows [256,384) = g gate -> tanh; wave-uniform branch (32 rows/wave)
            gates_sh[r] = is_g_gate ? tanh_f(g) : sigmoid_f(g);
        }
        __syncthreads();
        if (t < HDIM) {
            const float ig = gates_sh[t];
            const float fg = gates_sh[t + HDIM];
            const float gg = gates_sh[t + 2 * HDIM];
            const float og = gates_sh[t + 3 * HDIM];
            c = __builtin_fmaf(fg, c, ig * gg);
            h_sh[t] = og * tanh_f(c);
        }
        __syncthreads();
    }

    if (t < HDIM) h_all[(size_t)seq * HDIM + t] = h_sh[t];
}

__global__ void __launch_bounds__(64)
fc_kernel(const float* __restrict__ h_all, const float* __restrict__ fc_w,
          const float* __restrict__ fc_b, float* __restrict__ out)
{
    const int blk = blockIdx.x;        // 0..1407 == b*22 + p
    const int b   = blk / 22;
    const int t   = threadIdx.x;       // 0..63

    __shared__ __align__(16) float comb[2 * HDIM];
    for (int i = t; i < HDIM; i += 64) {
        comb[i]        = h_all[(size_t)blk * HDIM + i];
        comb[HDIM + i] = h_all[(size_t)(NPLAYER + b) * HDIM + i];
    }
    __syncthreads();

    if (t < 40) {
        const float* wr = fc_w + (size_t)t * 2 * HDIM;
        float acc = fc_b[t];
        float a1 = 0.0f, a2 = 0.0f, a3 = 0.0f;
        #pragma unroll
        for (int k = 0; k < 2 * HDIM; k += 4) {
            float4 wv = *(const float4*)(wr + k);
            float4 cv = *(const float4*)(comb + k);
            acc = __builtin_fmaf(wv.x, cv.x, acc);
            a1  = __builtin_fmaf(wv.y, cv.y, a1);
            a2  = __builtin_fmaf(wv.z, cv.z, a2);
            a3  = __builtin_fmaf(wv.w, cv.w, a3);
        }
        out[(size_t)blk * 40 + t] = acc + (a1 + a2) + a3;
    }
}

extern "C" void kernel_launch(void* const* d_in, const int* in_sizes, int n_in,
                              void* d_out, int out_size, void* d_ws, size_t ws_size,
                              hipStream_t stream) {
    const float* x_players = (const float*)d_in[0];
    const float* x_ball    = (const float*)d_in[1];
    const float* p_w_ih    = (const float*)d_in[2];
    const float* p_w_hh    = (const float*)d_in[3];
    const float* p_b_ih    = (const float*)d_in[4];
    const float* p_b_hh    = (const float*)d_in[5];
    const float* b_w_ih    = (const float*)d_in[6];
    const float* b_w_hh    = (const float*)d_in[7];
    const float* b_b_ih    = (const float*)d_in[8];
    const float* b_b_hh    = (const float*)d_in[9];
    const float* fc_w      = (const float*)d_in[10];
    const float* fc_b      = (const float*)d_in[11];

    float* h_all = (float*)d_ws;   // NSEQ * HDIM floats = 753,664 B

    lstm_kernel<<<dim3(NSEQ), dim3(1024), 0, stream>>>(
        x_players, x_ball, p_w_ih, p_w_hh, p_b_ih, p_b_hh,
        b_w_ih, b_w_hh, b_b_ih, b_b_hh, h_all);

    fc_kernel<<<dim3(NPLAYER), dim3(64), 0, stream>>>(
        h_all, fc_w, fc_b, (float*)d_out);
}

// Round 3
// 338.515 us; speedup vs baseline: 3.1151x; 3.1151x over previous
//
#include <hip/hip_runtime.h>

// TeamMovementModel R3: MFMA batched-sequence LSTM.
// Block = 16 sequences x all 128 steps. gates(512x16) = W_aug(512x160) @ B(160x16)
// per step with mfma_f32_16x16x32_bf16. W held in VGPRs as MFMA A-fragments
// (bf16 hi+lo split -> near-fp32 weight precision). Aug columns 128..132 carry
// [x0_hi, x1_hi, 1, x0_lo, x1_lo] so W_ih@x + bias is fused into the GEMM.
// h round-trips LDS as bf16 (B layout [n][k], stride 168 bf16 = 84 dwords:
// 8-lane groups cover all 32 banks). Gates LDS stride 18 floats -> 2-way only.
// 92 blocks (1472/16), 512 threads (8 waves x 64 gate rows each).

#define HDIM 128
#define TSTEPS 128
#define NPLAYER 1408
#define NSEQ 1472
#define NB 16
#define NBLK (NSEQ / NB)        // 92
#define NPBLK (NPLAYER / NB)    // 88
#define KT 5                    // k-tiles of 32 (K_aug = 160)
#define BSTR 168                // bf16 per B row (84 dwords, 16B-aligned rows)
#define GSTR 18                 // floats per gate row (pad: 2-way conflicts only)

typedef short bf16x8 __attribute__((ext_vector_type(8)));
typedef short bf16x4 __attribute__((ext_vector_type(4)));
typedef float f32x4  __attribute__((ext_vector_type(4)));

static __device__ __forceinline__ short f2bf(float f) {
    union { float f; unsigned u; } v; v.f = f;
    unsigned r = (v.u + 0x7FFFu + ((v.u >> 16) & 1u)) >> 16;
    return (short)r;
}
static __device__ __forceinline__ float bf2f(short s) {
    union { float f; unsigned u; } v; v.u = ((unsigned)(unsigned short)s) << 16;
    return v.f;
}
__device__ __forceinline__ float rcp_fast(float x) { return __builtin_amdgcn_rcpf(x); }
__device__ __forceinline__ float sigmoid_f(float x) { return rcp_fast(1.0f + __expf(-x)); }
__device__ __forceinline__ float tanh_f(float x) {
    return 1.0f - 2.0f * rcp_fast(__expf(2.0f * x) + 1.0f);
}

__global__ void __launch_bounds__(512, 2)
lstm_kernel(const float* __restrict__ x_players, const float* __restrict__ x_ball,
            const float* __restrict__ p_w_ih, const float* __restrict__ p_w_hh,
            const float* __restrict__ p_b_ih, const float* __restrict__ p_b_hh,
            const float* __restrict__ b_w_ih, const float* __restrict__ b_w_hh,
            const float* __restrict__ b_b_ih, const float* __restrict__ b_b_hh,
            float* __restrict__ h_all)
{
    const int tid  = threadIdx.x;
    const int blk  = blockIdx.x;          // 0..91; 88..91 are ball blocks
    const int wv   = tid >> 6;            // wave 0..7 -> gate rows [64*wv, 64*wv+64)
    const int lane = tid & 63;
    const int nn   = lane & 15;           // MFMA n (sequence within block)
    const int q    = lane >> 4;           // MFMA quad

    const bool ball = (blk >= NPBLK);
    const float* w_ih = ball ? b_w_ih : p_w_ih;
    const float* w_hh = ball ? b_w_hh : p_w_hh;
    const float* bih  = ball ? b_b_ih : p_b_ih;
    const float* bhh  = ball ? b_b_hh : p_b_hh;
    const float* xg   = ball ? (x_ball    + (size_t)(blk - NPBLK) * NB * TSTEPS * 2)
                             : (x_players + (size_t)blk * NB * TSTEPS * 2);

    __shared__ __align__(16) short b_sh[NB * BSTR];        // B operand, bf16
    __shared__ float g_sh[512 * GSTR];                     // activated gates
    __shared__ __align__(16) float x_sh[NB * TSTEPS * 2];  // staged inputs

    // ---- stage x (contiguous copy, coalesced) ----
    for (int i = tid; i < NB * TSTEPS * 2; i += 512) x_sh[i] = xg[i];
    // ---- zero B (h rows = h(0) = 0, pad rows = 0) ----
    for (int i = tid; i < NB * BSTR / 2; i += 512) ((int*)b_sh)[i] = 0;

    // ---- A fragments: W_aug rows, bf16 hi+lo, register-resident ----
    // A layout (16x16x32): a[j] = A[m = lane&15][k = 32*kt + 8*q + j]
    bf16x8 ah[4][KT], al[4][KT];
    #pragma unroll
    for (int mi = 0; mi < 4; ++mi) {
        const int r = wv * 64 + mi * 16 + nn;
        const float* wr = w_hh + (size_t)r * HDIM;
        const float wib0 = w_ih[2 * r], wib1 = w_ih[2 * r + 1];
        const float bsum = bih[r] + bhh[r];
        #pragma unroll
        for (int kt = 0; kt < KT; ++kt) {
            float v[8];
            if (kt < 4) {
                const float* p = wr + kt * 32 + q * 8;
                #pragma unroll
                for (int j = 0; j < 8; ++j) v[j] = p[j];
            } else {
                #pragma unroll
                for (int j = 0; j < 8; ++j) v[j] = 0.0f;
                if (q == 0) { v[0] = wib0; v[1] = wib1; v[2] = bsum; v[3] = wib0; v[4] = wib1; }
            }
            bf16x8 h8, l8;
            #pragma unroll
            for (int j = 0; j < 8; ++j) {
                short hi = f2bf(v[j]);
                h8[j] = hi;
                l8[j] = f2bf(v[j] - bf2f(hi));
            }
            ah[mi][kt] = h8; al[mi][kt] = l8;
        }
    }

    float c0 = 0.f, c1 = 0.f, c2 = 0.f, c3 = 0.f;  // cell state (phase-3 role)
    __syncthreads();  // zero-fill done before x-row writes touch B

    // ---- x rows of B for step 0: cols 128..132 = [x0h, x1h, 1, x0l, x1l] ----
    if (tid < NB) {
        const float x0 = x_sh[tid * 256 + 0], x1 = x_sh[tid * 256 + 1];
        short* br = b_sh + tid * BSTR;
        short x0h = f2bf(x0), x1h = f2bf(x1);
        br[128] = x0h; br[129] = x1h; br[130] = (short)0x3F80;
        br[131] = f2bf(x0 - bf2f(x0h)); br[132] = f2bf(x1 - bf2f(x1h));
    }
    __syncthreads();

    const bool isg = (wv == 4 || wv == 5);   // rows [256,384) -> tanh (wave-uniform)
    const int n2 = tid & 15, h4 = tid >> 4;  // phase-3 ownership: (seq n2, h-rows 4*h4..+3)

    for (int s = 0; s < TSTEPS; ++s) {
        // ---- phase 1: MFMA.  B layout: b[j] = B[k = 32*kt + 8*q + j][n = lane&15] ----
        bf16x8 bfr[KT];
        #pragma unroll
        for (int kt = 0; kt < KT; ++kt)
            bfr[kt] = *(const bf16x8*)&b_sh[nn * BSTR + kt * 32 + q * 8];
        f32x4 acc[4];
        #pragma unroll
        for (int mi = 0; mi < 4; ++mi) acc[mi] = (f32x4){0.f, 0.f, 0.f, 0.f};
        #pragma unroll
        for (int kt = 0; kt < KT; ++kt)
            #pragma unroll
            for (int mi = 0; mi < 4; ++mi) {
                acc[mi] = __builtin_amdgcn_mfma_f32_16x16x32_bf16(ah[mi][kt], bfr[kt], acc[mi], 0, 0, 0);
                acc[mi] = __builtin_amdgcn_mfma_f32_16x16x32_bf16(al[mi][kt], bfr[kt], acc[mi], 0, 0, 0);
            }

        // ---- phase 2: activation, C layout row = 4*q + reg, col = nn ----
        #pragma unroll
        for (int mi = 0; mi < 4; ++mi)
            #pragma unroll
            for (int reg = 0; reg < 4; ++reg) {
                const float v = acc[mi][reg];
                const float a = isg ? tanh_f(v) : sigmoid_f(v);
                g_sh[(wv * 64 + mi * 16 + q * 4 + reg) * GSTR + nn] = a;
            }
        __syncthreads();

        // ---- phase 3: cell update for 4 h-rows of one sequence ----
        {
            float hv[4]; short hh[4];
            float* cc[4] = {&c0, &c1, &c2, &c3};
            #pragma unroll
            for (int j = 0; j < 4; ++j) {
                const int r0 = 4 * h4 + j;
                const float ig = g_sh[r0 * GSTR + n2];
                const float fg = g_sh[(r0 + 128) * GSTR + n2];
                const float gg = g_sh[(r0 + 256) * GSTR + n2];
                const float og = g_sh[(r0 + 384) * GSTR + n2];
                *cc[j] = __builtin_fmaf(fg, *cc[j], ig * gg);
                hv[j] = og * tanh_f(*cc[j]);
                hh[j] = f2bf(hv[j]);
            }
            *(bf16x4*)&b_sh[n2 * BSTR + 4 * h4] = (bf16x4){hh[0], hh[1], hh[2], hh[3]};
            if (s == TSTEPS - 1) {
                float* hp = h_all + (size_t)(blk * NB + n2) * HDIM + 4 * h4;
                #pragma unroll
                for (int j = 0; j < 4; ++j) hp[j] = hv[j];
            }
            if (tid < NB && s + 1 < TSTEPS) {
                const float x0 = x_sh[tid * 256 + 2 * (s + 1)];
                const float x1 = x_sh[tid * 256 + 2 * (s + 1) + 1];
                short* br = b_sh + tid * BSTR;
                short x0h = f2bf(x0), x1h = f2bf(x1);
                br[128] = x0h; br[129] = x1h; br[130] = (short)0x3F80;
                br[131] = f2bf(x0 - bf2f(x0h)); br[132] = f2bf(x1 - bf2f(x1h));
            }
        }
        __syncthreads();
    }
}

__global__ void __launch_bounds__(64)
fc_kernel(const float* __restrict__ h_all, const float* __restrict__ fc_w,
          const float* __restrict__ fc_b, float* __restrict__ out)
{
    const int blk = blockIdx.x;        // 0..1407 == b*22 + p
    const int b   = blk / 22;
    const int t   = threadIdx.x;       // 0..63

    __shared__ __align__(16) float comb[2 * HDIM];
    for (int i = t; i < HDIM; i += 64) {
        comb[i]        = h_all[(size_t)blk * HDIM + i];
        comb[HDIM + i] = h_all[(size_t)(NPLAYER + b) * HDIM + i];
    }
    __syncthreads();

    if (t < 40) {
        const float* wr = fc_w + (size_t)t * 2 * HDIM;
        float acc = fc_b[t];
        float a1 = 0.0f, a2 = 0.0f, a3 = 0.0f;
        #pragma unroll
        for (int k = 0; k < 2 * HDIM; k += 4) {
            float4 wv = *(const float4*)(wr + k);
            float4 cv = *(const float4*)(comb + k);
            acc = __builtin_fmaf(wv.x, cv.x, acc);
            a1  = __builtin_fmaf(wv.y, cv.y, a1);
            a2  = __builtin_fmaf(wv.z, cv.z, a2);
            a3  = __builtin_fmaf(wv.w, cv.w, a3);
        }
        out[(size_t)blk * 40 + t] = acc + (a1 + a2) + a3;
    }
}

extern "C" void kernel_launch(void* const* d_in, const int* in_sizes, int n_in,
                              void* d_out, int out_size, void* d_ws, size_t ws_size,
                              hipStream_t stream) {
    const float* x_players = (const float*)d_in[0];
    const float* x_ball    = (const float*)d_in[1];
    const float* p_w_ih    = (const float*)d_in[2];
    const float* p_w_hh    = (const float*)d_in[3];
    const float* p_b_ih    = (const float*)d_in[4];
    const float* p_b_hh    = (const float*)d_in[5];
    const float* b_w_ih    = (const float*)d_in[6];
    const float* b_w_hh    = (const float*)d_in[7];
    const float* b_b_ih    = (const float*)d_in[8];
    const float* b_b_hh    = (const float*)d_in[9];
    const float* fc_w      = (const float*)d_in[10];
    const float* fc_b      = (const float*)d_in[11];

    float* h_all = (float*)d_ws;   // NSEQ * HDIM floats

    lstm_kernel<<<dim3(NBLK), dim3(512), 0, stream>>>(
        x_players, x_ball, p_w_ih, p_w_hh, p_b_ih, p_b_hh,
        b_w_ih, b_w_hh, b_b_ih, b_b_hh, h_all);

    fc_kernel<<<dim3(NPLAYER), dim3(64), 0, stream>>>(
        h_all, fc_w, fc_b, (float*)d_out);
}

// Round 4
// 292.278 us; speedup vs baseline: 3.6079x; 1.1582x over previous
//
#include <hip/hip_runtime.h>

// TeamMovementModel R4: fp16 MFMA batched LSTM, 8 seqs/block -> 184 blocks.
// gates(512x16cols, 8 used) = W_aug(512x160) @ B(160x16) per step via
// mfma_f32_16x16x32_f16. Single-level fp16 weights (11-bit mantissa beats the
// R3 bf16 hi/lo on the dominant h-quantization term; R3 passed at 9.8e-4 with
// bf16 h). 80 weight VGPRs/thread -> no spill (R3 spilled: WRITE_SIZE 17.5MB).
// Aug cols 128..130 = [x0, x1, 1] fold W_ih@x + bias into the GEMM.
// 512 threads = 8 waves x 64 gate rows; cols 8..15 of the MFMA are unused
// padding (writes guarded; garbage contained).

#define HDIM 128
#define TSTEPS 128
#define NPLAYER 1408
#define NSEQ 1472
#define NB 8
#define NBLK (NSEQ / NB)        // 184
#define NPBLK (NPLAYER / NB)    // 176
#define KT 5                    // k-tiles of 32 (K_aug = 160)
#define BSTR 168                // fp16 per B row (336 B, 16B-aligned rows)
#define GSTR 9                  // floats per gate row

typedef _Float16 f16x8 __attribute__((ext_vector_type(8)));
typedef _Float16 f16x4 __attribute__((ext_vector_type(4)));
typedef float    f32x4 __attribute__((ext_vector_type(4)));

__device__ __forceinline__ float rcp_fast(float x) { return __builtin_amdgcn_rcpf(x); }
__device__ __forceinline__ float sigmoid_f(float x) { return rcp_fast(1.0f + __expf(-x)); }
__device__ __forceinline__ float tanh_f(float x) {
    return 1.0f - 2.0f * rcp_fast(__expf(2.0f * x) + 1.0f);
}

__global__ void __launch_bounds__(512)
lstm_kernel(const float* __restrict__ x_players, const float* __restrict__ x_ball,
            const float* __restrict__ p_w_ih, const float* __restrict__ p_w_hh,
            const float* __restrict__ p_b_ih, const float* __restrict__ p_b_hh,
            const float* __restrict__ b_w_ih, const float* __restrict__ b_w_hh,
            const float* __restrict__ b_b_ih, const float* __restrict__ b_b_hh,
            float* __restrict__ h_all)
{
    const int tid  = threadIdx.x;
    const int blk  = blockIdx.x;          // 0..183; 176..183 are ball blocks
    const int wv   = tid >> 6;            // wave 0..7 -> gate rows [64*wv, 64*wv+64)
    const int lane = tid & 63;
    const int nn   = lane & 15;           // MFMA n (sequence col)
    const int q    = lane >> 4;           // MFMA quad

    const bool ball = (blk >= NPBLK);
    const float* w_ih = ball ? b_w_ih : p_w_ih;
    const float* w_hh = ball ? b_w_hh : p_w_hh;
    const float* bih  = ball ? b_b_ih : p_b_ih;
    const float* bhh  = ball ? b_b_hh : p_b_hh;
    const float* xg   = ball ? (x_ball    + (size_t)(blk - NPBLK) * NB * TSTEPS * 2)
                             : (x_players + (size_t)blk * NB * TSTEPS * 2);

    __shared__ __align__(16) _Float16 b_sh[16 * BSTR];     // B operand (rows=seq, 8..15 zero)
    __shared__ float g_sh[512 * GSTR];                     // activated gates
    __shared__ __align__(16) float x_sh[NB * TSTEPS * 2];  // staged inputs

    for (int i = tid; i < NB * TSTEPS * 2; i += 512) x_sh[i] = xg[i];
    for (int i = tid; i < 16 * BSTR / 2; i += 512) ((int*)b_sh)[i] = 0;

    // ---- A fragments: W_aug rows -> fp16 registers.  a[j] = A[m=lane&15][k=32kt+8q+j]
    f16x8 afr[4][KT];
    #pragma unroll
    for (int mi = 0; mi < 4; ++mi) {
        const int r = wv * 64 + mi * 16 + nn;
        const float* wr = w_hh + (size_t)r * HDIM;
        const float wib0 = w_ih[2 * r], wib1 = w_ih[2 * r + 1];
        const float bsum = bih[r] + bhh[r];
        #pragma unroll
        for (int kt = 0; kt < KT; ++kt) {
            f16x8 a8;
            if (kt < 4) {
                const float* p = wr + kt * 32 + q * 8;
                #pragma unroll
                for (int j = 0; j < 8; ++j) a8[j] = (_Float16)p[j];
            } else {
                #pragma unroll
                for (int j = 0; j < 8; ++j) a8[j] = (_Float16)0.0f;
                if (q == 0) { a8[0] = (_Float16)wib0; a8[1] = (_Float16)wib1; a8[2] = (_Float16)bsum; }
            }
            afr[mi][kt] = a8;
        }
    }

    float c[4] = {0.f, 0.f, 0.f, 0.f};
    __syncthreads();

    // x row of B for step 0: cols 128..130 = [x0, x1, 1]
    if (tid < NB) {
        _Float16* br = b_sh + tid * BSTR;
        br[128] = (_Float16)x_sh[tid * 256 + 0];
        br[129] = (_Float16)x_sh[tid * 256 + 1];
        br[130] = (_Float16)1.0f;
    }
    __syncthreads();

    const bool isg = (wv == 4 || wv == 5);   // rows [256,384) -> tanh
    const int n2 = tid & 15, h4 = tid >> 4;  // phase-3: (seq n2, h-rows 4*h4..+3)

    for (int s = 0; s < TSTEPS; ++s) {
        // ---- phase 1: MFMA. b[j] = B[k=32kt+8q+j][n=lane&15] ----
        f16x8 bfr[KT];
        #pragma unroll
        for (int kt = 0; kt < KT; ++kt)
            bfr[kt] = *(const f16x8*)&b_sh[nn * BSTR + kt * 32 + q * 8];
        f32x4 acc[4];
        #pragma unroll
        for (int mi = 0; mi < 4; ++mi) acc[mi] = (f32x4){0.f, 0.f, 0.f, 0.f};
        #pragma unroll
        for (int kt = 0; kt < KT; ++kt)
            #pragma unroll
            for (int mi = 0; mi < 4; ++mi)
                acc[mi] = __builtin_amdgcn_mfma_f32_16x16x32_f16(afr[mi][kt], bfr[kt], acc[mi], 0, 0, 0);

        // ---- phase 2: activations. C layout: row = 4q+reg, col = nn ----
        if (nn < NB) {
            #pragma unroll
            for (int mi = 0; mi < 4; ++mi)
                #pragma unroll
                for (int reg = 0; reg < 4; ++reg) {
                    const float v = acc[mi][reg];
                    g_sh[(wv * 64 + mi * 16 + q * 4 + reg) * GSTR + nn] = isg ? tanh_f(v) : sigmoid_f(v);
                }
        }
        __syncthreads();

        // ---- phase 3: cell update (seq n2 < 8, h-rows 4*h4..4*h4+3) ----
        if (n2 < NB) {
            float hv[4];
            #pragma unroll
            for (int j = 0; j < 4; ++j) {
                const int r0 = 4 * h4 + j;
                const float ig = g_sh[r0 * GSTR + n2];
                const float fg = g_sh[(r0 + 128) * GSTR + n2];
                const float gg = g_sh[(r0 + 256) * GSTR + n2];
                const float og = g_sh[(r0 + 384) * GSTR + n2];
                c[j] = __builtin_fmaf(fg, c[j], ig * gg);
                hv[j] = og * tanh_f(c[j]);
            }
            *(f16x4*)&b_sh[n2 * BSTR + 4 * h4] =
                (f16x4){(_Float16)hv[0], (_Float16)hv[1], (_Float16)hv[2], (_Float16)hv[3]};
            if (s == TSTEPS - 1) {
                float* hp = h_all + (size_t)(blk * NB + n2) * HDIM + 4 * h4;
                #pragma unroll
                for (int j = 0; j < 4; ++j) hp[j] = hv[j];
            }
        }
        if (tid < NB && s + 1 < TSTEPS) {
            _Float16* br = b_sh + tid * BSTR;
            br[128] = (_Float16)x_sh[tid * 256 + 2 * (s + 1)];
            br[129] = (_Float16)x_sh[tid * 256 + 2 * (s + 1) + 1];
        }
        __syncthreads();
    }
}

__global__ void __launch_bounds__(64)
fc_kernel(const float* __restrict__ h_all, const float* __restrict__ fc_w,
          const float* __restrict__ fc_b, float* __restrict__ out)
{
    const int blk = blockIdx.x;        // 0..1407 == b*22 + p
    const int b   = blk / 22;
    const int t   = threadIdx.x;       // 0..63

    __shared__ __align__(16) float comb[2 * HDIM];
    for (int i = t; i < HDIM; i += 64) {
        comb[i]        = h_all[(size_t)blk * HDIM + i];
        comb[HDIM + i] = h_all[(size_t)(NPLAYER + b) * HDIM + i];
    }
    __syncthreads();

    if (t < 40) {
        const float* wr = fc_w + (size_t)t * 2 * HDIM;
        float acc = fc_b[t];
        float a1 = 0.0f, a2 = 0.0f, a3 = 0.0f;
        #pragma unroll
        for (int k = 0; k < 2 * HDIM; k += 4) {
            float4 wv = *(const float4*)(wr + k);
            float4 cv = *(const float4*)(comb + k);
            acc = __builtin_fmaf(wv.x, cv.x, acc);
            a1  = __builtin_fmaf(wv.y, cv.y, a1);
            a2  = __builtin_fmaf(wv.z, cv.z, a2);
            a3  = __builtin_fmaf(wv.w, cv.w, a3);
        }
        out[(size_t)blk * 40 + t] = acc + (a1 + a2) + a3;
    }
}

extern "C" void kernel_launch(void* const* d_in, const int* in_sizes, int n_in,
                              void* d_out, int out_size, void* d_ws, size_t ws_size,
                              hipStream_t stream) {
    const float* x_players = (const float*)d_in[0];
    const float* x_ball    = (const float*)d_in[1];
    const float* p_w_ih    = (const float*)d_in[2];
    const float* p_w_hh    = (const float*)d_in[3];
    const float* p_b_ih    = (const float*)d_in[4];
    const float* p_b_hh    = (const float*)d_in[5];
    const float* b_w_ih    = (const float*)d_in[6];
    const float* b_w_hh    = (const float*)d_in[7];
    const float* b_b_ih    = (const float*)d_in[8];
    const float* b_b_hh    = (const float*)d_in[9];
    const float* fc_w      = (const float*)d_in[10];
    const float* fc_b      = (const float*)d_in[11];

    float* h_all = (float*)d_ws;   // NSEQ * HDIM floats

    lstm_kernel<<<dim3(NBLK), dim3(512), 0, stream>>>(
        x_players, x_ball, p_w_ih, p_w_hh, p_b_ih, p_b_hh,
        b_w_ih, b_w_hh, b_b_ih, b_b_hh, h_all);

    fc_kernel<<<dim3(NPLAYER), dim3(64), 0, stream>>>(
        h_all, fc_w, fc_b, (float*)d_out);
}

// Round 5
// 263.195 us; speedup vs baseline: 4.0066x; 1.1105x over previous
//
#include <hip/hip_runtime.h>

// TeamMovementModel R5: fp16 MFMA batched LSTM, 8 seqs/block, 184 blocks.
// Fixes vs R4 (VGPR=76 proved A-fragments were rematerialized every step):
//  - amdgpu_waves_per_eu(2,2): exact occupancy 1 block/CU -> 256-reg budget,
//    removes the allocator's remat-for-occupancy incentive.
//  - volatile asm pin on each A-fragment at init: immovable def, cannot sink.
//  - shfl_xor(8) C-swap: every lane activates 8 useful gates (was 16, half waste).
//  - g_sh stride 10 (was 9): gate-store bank pattern 4-way -> 2-way (free).
//  - FC: one block per batch (64 blocks x 512 thr), comb in LDS.

#define HDIM 128
#define TSTEPS 128
#define NPLAYER 1408
#define NSEQ 1472
#define NB 8
#define NBLK (NSEQ / NB)        // 184
#define NPBLK (NPLAYER / NB)    // 176
#define KT 5                    // k-tiles of 32 (K_aug = 160)
#define BSTR 168                // fp16 per B row
#define GSTR 10                 // floats per gate row (2-way banks only)

typedef _Float16 f16x8 __attribute__((ext_vector_type(8)));
typedef _Float16 f16x4 __attribute__((ext_vector_type(4)));
typedef float    f32x4 __attribute__((ext_vector_type(4)));

__device__ __forceinline__ float rcp_fast(float x) { return __builtin_amdgcn_rcpf(x); }
__device__ __forceinline__ float sigmoid_f(float x) { return rcp_fast(1.0f + __expf(-x)); }
__device__ __forceinline__ float tanh_f(float x) {
    return 1.0f - 2.0f * rcp_fast(__expf(2.0f * x) + 1.0f);
}

__global__ void __launch_bounds__(512)
__attribute__((amdgpu_waves_per_eu(2, 2)))
lstm_kernel(const float* __restrict__ x_players, const float* __restrict__ x_ball,
            const float* __restrict__ p_w_ih, const float* __restrict__ p_w_hh,
            const float* __restrict__ p_b_ih, const float* __restrict__ p_b_hh,
            const float* __restrict__ b_w_ih, const float* __restrict__ b_w_hh,
            const float* __restrict__ b_b_ih, const float* __restrict__ b_b_hh,
            float* __restrict__ h_all)
{
    const int tid  = threadIdx.x;
    const int blk  = blockIdx.x;          // 0..183; 176..183 ball
    const int wv   = tid >> 6;            // wave -> gate rows [64*wv, 64*wv+64)
    const int lane = tid & 63;
    const int nn   = lane & 15;           // MFMA n (sequence col)
    const int q    = lane >> 4;           // MFMA quad

    const bool ball = (blk >= NPBLK);
    const float* w_ih = ball ? b_w_ih : p_w_ih;
    const float* w_hh = ball ? b_w_hh : p_w_hh;
    const float* bih  = ball ? b_b_ih : p_b_ih;
    const float* bhh  = ball ? b_b_hh : p_b_hh;
    const float* xg   = ball ? (x_ball    + (size_t)(blk - NPBLK) * NB * TSTEPS * 2)
                             : (x_players + (size_t)blk * NB * TSTEPS * 2);

    __shared__ __align__(16) _Float16 b_sh[16 * BSTR];
    __shared__ float g_sh[512 * GSTR];
    __shared__ __align__(16) float x_sh[NB * TSTEPS * 2];

    for (int i = tid; i < NB * TSTEPS * 2; i += 512) x_sh[i] = xg[i];
    for (int i = tid; i < 16 * BSTR / 2; i += 512) ((int*)b_sh)[i] = 0;

    // ---- A fragments: W_aug rows -> fp16 regs. a[j] = A[m=lane&15][k=32kt+8q+j]
    f16x8 afr[4][KT];
    #pragma unroll
    for (int mi = 0; mi < 4; ++mi) {
        const int r = wv * 64 + mi * 16 + nn;
        const float* wr = w_hh + (size_t)r * HDIM;
        const float wib0 = w_ih[2 * r], wib1 = w_ih[2 * r + 1];
        const float bsum = bih[r] + bhh[r];
        #pragma unroll
        for (int kt = 0; kt < KT; ++kt) {
            f16x8 a8;
            if (kt < 4) {
                const float* p = wr + kt * 32 + q * 8;
                #pragma unroll
                for (int j = 0; j < 8; ++j) a8[j] = (_Float16)p[j];
            } else {
                #pragma unroll
                for (int j = 0; j < 8; ++j) a8[j] = (_Float16)0.0f;
                if (q == 0) { a8[0] = (_Float16)wib0; a8[1] = (_Float16)wib1; a8[2] = (_Float16)bsum; }
            }
            afr[mi][kt] = a8;
            // pin: immovable def -> cannot be rematerialized inside the loop
            asm volatile("" : "+v"(afr[mi][kt]));
        }
    }

    float c[4] = {0.f, 0.f, 0.f, 0.f};
    __syncthreads();

    if (tid < NB) {
        _Float16* br = b_sh + tid * BSTR;
        br[128] = (_Float16)x_sh[tid * 256 + 0];
        br[129] = (_Float16)x_sh[tid * 256 + 1];
        br[130] = (_Float16)1.0f;
    }
    __syncthreads();

    const bool isg = (wv == 4 || wv == 5);   // rows [256,384) -> tanh
    const int n2 = tid & 15, h4 = tid >> 4;

    for (int s = 0; s < TSTEPS; ++s) {
        // ---- phase 1: MFMA. b[j] = B[k=32kt+8q+j][n=lane&15] ----
        f16x8 bfr[KT];
        #pragma unroll
        for (int kt = 0; kt < KT; ++kt)
            bfr[kt] = *(const f16x8*)&b_sh[nn * BSTR + kt * 32 + q * 8];
        f32x4 acc[4];
        #pragma unroll
        for (int mi = 0; mi < 4; ++mi) acc[mi] = (f32x4){0.f, 0.f, 0.f, 0.f};
        #pragma unroll
        for (int kt = 0; kt < KT; ++kt)
            #pragma unroll
            for (int mi = 0; mi < 4; ++mi)
                acc[mi] = __builtin_amdgcn_mfma_f32_16x16x32_f16(afr[mi][kt], bfr[kt], acc[mi], 0, 0, 0);

        // ---- phase 2: swap so every lane activates 8 USEFUL gates ----
        // lane(q,nn<8):  acc[0],acc[1]      -> rows wv*64 + {0,1}*16 + 4q+reg, col nn
        // lane(q,nn>=8): swapped acc[2],acc[3] (from lane nn-8)
        //                -> rows wv*64 + {2,3}*16 + 4q+reg, col nn-8
        f32x4 sw2, sw3;
        #pragma unroll
        for (int j = 0; j < 4; ++j) {
            sw2[j] = __shfl_xor(acc[2][j], 8);
            sw3[j] = __shfl_xor(acc[3][j], 8);
        }
        {
            const int col = (nn < 8) ? nn : (nn - 8);
            const int mbase = (nn < 8) ? 0 : 2;
            f32x4 v0 = (nn < 8) ? acc[0] : sw2;
            f32x4 v1 = (nn < 8) ? acc[1] : sw3;
            #pragma unroll
            for (int reg = 0; reg < 4; ++reg) {
                const float a0 = v0[reg], a1 = v1[reg];
                const int r0 = wv * 64 + mbase * 16 + q * 4 + reg;
                g_sh[r0 * GSTR + col]        = isg ? tanh_f(a0) : sigmoid_f(a0);
                g_sh[(r0 + 16) * GSTR + col] = isg ? tanh_f(a1) : sigmoid_f(a1);
            }
        }
        __syncthreads();

        // ---- phase 3: cell update (seq n2 < 8, h-rows 4*h4..4*h4+3) ----
        if (n2 < NB) {
            float hv[4];
            #pragma unroll
            for (int j = 0; j < 4; ++j) {
                const int r0 = 4 * h4 + j;
                const float ig = g_sh[r0 * GSTR + n2];
                const float fg = g_sh[(r0 + 128) * GSTR + n2];
                const float gg = g_sh[(r0 + 256) * GSTR + n2];
                const float og = g_sh[(r0 + 384) * GSTR + n2];
                c[j] = __builtin_fmaf(fg, c[j], ig * gg);
                hv[j] = og * tanh_f(c[j]);
            }
            *(f16x4*)&b_sh[n2 * BSTR + 4 * h4] =
                (f16x4){(_Float16)hv[0], (_Float16)hv[1], (_Float16)hv[2], (_Float16)hv[3]};
            if (s == TSTEPS - 1) {
                float* hp = h_all + (size_t)(blk * NB + n2) * HDIM + 4 * h4;
                #pragma unroll
                for (int j = 0; j < 4; ++j) hp[j] = hv[j];
            }
        }
        if (tid < NB && s + 1 < TSTEPS) {
            _Float16* br = b_sh + tid * BSTR;
            br[128] = (_Float16)x_sh[tid * 256 + 2 * (s + 1)];
            br[129] = (_Float16)x_sh[tid * 256 + 2 * (s + 1) + 1];
        }
        __syncthreads();
    }
}

// FC: one block per batch b. comb = [22 player h ; ball h] staged in LDS,
// 880 outputs (22 players x 40 rows) over 512 threads.
__global__ void __launch_bounds__(512)
fc_kernel(const float* __restrict__ h_all, const float* __restrict__ fc_w,
          const float* __restrict__ fc_b, float* __restrict__ out)
{
    const int b   = blockIdx.x;        // 0..63
    const int tid = threadIdx.x;

    __shared__ __align__(16) float comb[23 * HDIM];   // 22 players + ball
    const float* hp = h_all + (size_t)b * 22 * HDIM;
    for (int i = tid; i < 22 * HDIM; i += 512) comb[i] = hp[i];
    const float* hb = h_all + (size_t)(NPLAYER + b) * HDIM;
    for (int i = tid; i < HDIM; i += 512) comb[22 * HDIM + i] = hb[i];
    __syncthreads();

    for (int o = tid; o < 22 * 40; o += 512) {
        const int p = o / 40, row = o - p * 40;
        const float* wr = fc_w + (size_t)row * 2 * HDIM;
        const float* cp = comb + p * HDIM;
        const float* cb = comb + 22 * HDIM;
        float a0 = fc_b[row], a1 = 0.f, a2 = 0.f, a3 = 0.f;
        #pragma unroll
        for (int k = 0; k < HDIM; k += 4) {
            float4 wv = *(const float4*)(wr + k);
            float4 cv = *(const float4*)(cp + k);
            a0 = __builtin_fmaf(wv.x, cv.x, a0);
            a1 = __builtin_fmaf(wv.y, cv.y, a1);
            a2 = __builtin_fmaf(wv.z, cv.z, a2);
            a3 = __builtin_fmaf(wv.w, cv.w, a3);
        }
        #pragma unroll
        for (int k = 0; k < HDIM; k += 4) {
            float4 wv = *(const float4*)(wr + HDIM + k);
            float4 cv = *(const float4*)(cb + k);
            a0 = __builtin_fmaf(wv.x, cv.x, a0);
            a1 = __builtin_fmaf(wv.y, cv.y, a1);
            a2 = __builtin_fmaf(wv.z, cv.z, a2);
            a3 = __builtin_fmaf(wv.w, cv.w, a3);
        }
        out[(size_t)(b * 22 + p) * 40 + row] = (a0 + a1) + (a2 + a3);
    }
}

extern "C" void kernel_launch(void* const* d_in, const int* in_sizes, int n_in,
                              void* d_out, int out_size, void* d_ws, size_t ws_size,
                              hipStream_t stream) {
    const float* x_players = (const float*)d_in[0];
    const float* x_ball    = (const float*)d_in[1];
    const float* p_w_ih    = (const float*)d_in[2];
    const float* p_w_hh    = (const float*)d_in[3];
    const float* p_b_ih    = (const float*)d_in[4];
    const float* p_b_hh    = (const float*)d_in[5];
    const float* b_w_ih    = (const float*)d_in[6];
    const float* b_w_hh    = (const float*)d_in[7];
    const float* b_b_ih    = (const float*)d_in[8];
    const float* b_b_hh    = (const float*)d_in[9];
    const float* fc_w      = (const float*)d_in[10];
    const float* fc_b      = (const float*)d_in[11];

    float* h_all = (float*)d_ws;   // NSEQ * HDIM floats

    lstm_kernel<<<dim3(NBLK), dim3(512), 0, stream>>>(
        x_players, x_ball, p_w_ih, p_w_hh, p_b_ih, p_b_hh,
        b_w_ih, b_w_hh, b_b_ih, b_b_hh, h_all);

    fc_kernel<<<dim3(64), dim3(512), 0, stream>>>(
        h_all, fc_w, fc_b, (float*)d_out);
}

// Round 6
// 205.687 us; speedup vs baseline: 5.1268x; 1.2796x over previous
//
#include <hip/hip_runtime.h>

// TeamMovementModel R6: fp16 MFMA batched LSTM, 8 seqs/block, 184 blocks.
// Key changes vs R5 (VGPR=88 proved weights STILL rematerialized from cache
// every step -> ~320KB/CU/step L1 traffic = the 3.2Kcyc/step wall):
//  1. LOOP-CARRIED pin: asm volatile "+v" pins at the BOTTOM of the step loop.
//     A def-use chain across the backedge cannot be rematerialized.
//  2. h-row-major wave mapping: wave w owns h-rows [16w,16w+16); its 4 m-tiles
//     are gates i,f,g,o for those rows -> one lane holds all 4 gates of the
//     same (h-row, seq): cell update is register-local, g_sh eliminated,
//     double-buffered B -> ONE barrier per step.
//  3. x-projection + bias folded into acc init (48 pinned consts, 32 VALU) ->
//     4 k-tiles instead of 5, no per-step x writes into B.
// Lane (q,nn): after MFMA holds gates for (rows 16w+4q+{0..3}, col nn).
// shfl_xor(8) reg-split: lane nn<8 keeps regs {0,1}, partner nn^8 takes regs
// {2,3} -> every lane: 2 h-rows, 8 gate activations + 2 tanh(c). All values
// entering exp are real (no NaN risk from unused cols).

#define HDIM 128
#define TSTEPS 128
#define NPLAYER 1408
#define NSEQ 1472
#define NB 8
#define NBLK (NSEQ / NB)        // 184
#define NPBLK (NPLAYER / NB)    // 176
#define BSTR 136                // fp16 per B row (272 B: nn*272 mod 128 = 16nn -> 2-way max)
#define XSTR 258                // floats per x col (1032 B: col*8 dwords -> distinct banks)

typedef _Float16 f16x8 __attribute__((ext_vector_type(8)));
typedef _Float16 f16x2 __attribute__((ext_vector_type(2)));
typedef float    f32x4 __attribute__((ext_vector_type(4)));

__device__ __forceinline__ float rcp_fast(float x) { return __builtin_amdgcn_rcpf(x); }
__device__ __forceinline__ float sigmoid_f(float x) { return rcp_fast(1.0f + __expf(-x)); }
__device__ __forceinline__ float tanh_f(float x) {
    return 1.0f - 2.0f * rcp_fast(__expf(2.0f * x) + 1.0f);
}

__global__ void __launch_bounds__(512)
__attribute__((amdgpu_waves_per_eu(2, 2)))
lstm_kernel(const float* __restrict__ x_players, const float* __restrict__ x_ball,
            const float* __restrict__ p_w_ih, const float* __restrict__ p_w_hh,
            const float* __restrict__ p_b_ih, const float* __restrict__ p_b_hh,
            const float* __restrict__ b_w_ih, const float* __restrict__ b_w_hh,
            const float* __restrict__ b_b_ih, const float* __restrict__ b_b_hh,
            float* __restrict__ h_all)
{
    const int tid  = threadIdx.x;
    const int blk  = blockIdx.x;          // 0..183; 176..183 ball
    const int w    = tid >> 6;            // wave -> h-rows [16w, 16w+16)
    const int lane = tid & 63;
    const int nn   = lane & 15;           // MFMA n (col)
    const int q    = lane >> 4;           // MFMA quad

    const bool ball = (blk >= NPBLK);
    const float* w_ih = ball ? b_w_ih : p_w_ih;
    const float* w_hh = ball ? b_w_hh : p_w_hh;
    const float* bih  = ball ? b_b_ih : p_b_ih;
    const float* bhh  = ball ? b_b_hh : p_b_hh;
    const float* xg   = ball ? (x_ball    + (size_t)(blk - NPBLK) * NB * TSTEPS * 2)
                             : (x_players + (size_t)blk * NB * TSTEPS * 2);

    __shared__ __align__(16) _Float16 b_sh[2][16 * BSTR];  // rows 8..15 stay zero
    __shared__ __align__(16) float x_sh[NB * XSTR];

    for (int i = tid; i < NB * 256; i += 512)
        x_sh[(i >> 8) * XSTR + (i & 255)] = xg[i];
    for (int i = tid; i < 2 * 16 * BSTR / 2; i += 512)
        ((int*)b_sh)[i] = 0;

    // ---- A fragments: gate mi, rows mi*128 + 16w + m (m=nn), fp16 registers.
    // a[j] = A[m = lane&15][k = 32kt + 8q + j]
    f16x8 afr[4][4];
    #pragma unroll
    for (int mi = 0; mi < 4; ++mi) {
        const float* wr = w_hh + (size_t)(mi * HDIM + w * 16 + nn) * HDIM;
        #pragma unroll
        for (int kt = 0; kt < 4; ++kt) {
            const float* p = wr + kt * 32 + q * 8;
            f16x8 a8;
            #pragma unroll
            for (int j = 0; j < 8; ++j) a8[j] = (_Float16)p[j];
            afr[mi][kt] = a8;
        }
    }
    // ---- acc-init consts: rows rc = mi*128 + 16w + 4q + reg (C layout rows)
    f32x4 wi0v[4], wi1v[4], bsv[4];
    #pragma unroll
    for (int mi = 0; mi < 4; ++mi)
        #pragma unroll
        for (int reg = 0; reg < 4; ++reg) {
            const int rc = mi * HDIM + w * 16 + 4 * q + reg;
            wi0v[mi][reg] = w_ih[2 * rc];
            wi1v[mi][reg] = w_ih[2 * rc + 1];
            bsv[mi][reg]  = bih[rc] + bhh[rc];
        }

    const int colh   = nn & 7;                  // owned seq col
    const int rowoff = (nn < 8) ? 0 : 2;        // reg-split: owner {0,1}, partner {2,3}
    const int hrow   = w * 16 + 4 * q + rowoff; // first of 2 owned h-rows
    float c0 = 0.f, c1 = 0.f;

    __syncthreads();

    for (int s = 0; s < TSTEPS; ++s) {
        const int cur = s & 1, nxt = cur ^ 1;

        // ---- B frags from current buffer. b[j] = B[k=32kt+8q+j][n=nn] ----
        f16x8 bfr[4];
        const _Float16* bb = &b_sh[cur][nn * BSTR];
        #pragma unroll
        for (int kt = 0; kt < 4; ++kt)
            bfr[kt] = *(const f16x8*)(bb + kt * 32 + q * 8);

        // ---- acc init = W_ih @ x + bias (rank-2 + bias, in VALU) ----
        const float x0 = x_sh[colh * XSTR + 2 * s];
        const float x1 = x_sh[colh * XSTR + 2 * s + 1];
        f32x4 acc[4];
        #pragma unroll
        for (int mi = 0; mi < 4; ++mi)
            #pragma unroll
            for (int reg = 0; reg < 4; ++reg)
                acc[mi][reg] = __builtin_fmaf(wi0v[mi][reg], x0,
                               __builtin_fmaf(wi1v[mi][reg], x1, bsv[mi][reg]));

        // ---- 16 MFMA: gates += W_hh @ h ----
        #pragma unroll
        for (int kt = 0; kt < 4; ++kt)
            #pragma unroll
            for (int mi = 0; mi < 4; ++mi)
                acc[mi] = __builtin_amdgcn_mfma_f32_16x16x32_f16(afr[mi][kt], bfr[kt], acc[mi], 0, 0, 0);

        // ---- reg-split swap: each lane ends with 2 real preacts per gate ----
        float u[4][2];
        #pragma unroll
        for (int mi = 0; mi < 4; ++mi) {
            const float r2 = __shfl_xor(acc[mi][2], 8);
            const float r3 = __shfl_xor(acc[mi][3], 8);
            u[mi][0] = (nn < 8) ? acc[mi][0] : r2;
            u[mi][1] = (nn < 8) ? acc[mi][1] : r3;
        }
        const float i0 = sigmoid_f(u[0][0]), i1 = sigmoid_f(u[0][1]);
        const float f0 = sigmoid_f(u[1][0]), f1 = sigmoid_f(u[1][1]);
        const float g0 = tanh_f(u[2][0]),    g1 = tanh_f(u[2][1]);
        const float o0 = sigmoid_f(u[3][0]), o1 = sigmoid_f(u[3][1]);
        c0 = __builtin_fmaf(f0, c0, i0 * g0);
        c1 = __builtin_fmaf(f1, c1, i1 * g1);
        const float h0 = o0 * tanh_f(c0);
        const float h1 = o1 * tanh_f(c1);

        // ---- write h pair (fp16) into next buffer; one b32/lane ----
        *(f16x2*)&b_sh[nxt][colh * BSTR + hrow] = (f16x2){(_Float16)h0, (_Float16)h1};

        if (s == TSTEPS - 1) {
            float* hp = h_all + (size_t)(blk * NB + colh) * HDIM + hrow;
            hp[0] = h0; hp[1] = h1;
        }
        __syncthreads();

        // ---- loop-carried pins: weights cannot be rematerialized across the
        // backedge (R1..R5 failure mode). Empty asm, zero instructions. ----
        asm volatile("" :
            "+v"(afr[0][0]), "+v"(afr[0][1]), "+v"(afr[0][2]), "+v"(afr[0][3]),
            "+v"(afr[1][0]), "+v"(afr[1][1]), "+v"(afr[1][2]), "+v"(afr[1][3]),
            "+v"(afr[2][0]), "+v"(afr[2][1]), "+v"(afr[2][2]), "+v"(afr[2][3]),
            "+v"(afr[3][0]), "+v"(afr[3][1]), "+v"(afr[3][2]), "+v"(afr[3][3]));
        asm volatile("" :
            "+v"(wi0v[0]), "+v"(wi0v[1]), "+v"(wi0v[2]), "+v"(wi0v[3]),
            "+v"(wi1v[0]), "+v"(wi1v[1]), "+v"(wi1v[2]), "+v"(wi1v[3]),
            "+v"(bsv[0]),  "+v"(bsv[1]),  "+v"(bsv[2]),  "+v"(bsv[3]));
    }
}

// FC: one block per batch b. comb = [22 player h ; ball h] staged in LDS,
// 880 outputs (22 players x 40 rows) over 512 threads.
__global__ void __launch_bounds__(512)
fc_kernel(const float* __restrict__ h_all, const float* __restrict__ fc_w,
          const float* __restrict__ fc_b, float* __restrict__ out)
{
    const int b   = blockIdx.x;        // 0..63
    const int tid = threadIdx.x;

    __shared__ __align__(16) float comb[23 * HDIM];   // 22 players + ball
    const float* hp = h_all + (size_t)b * 22 * HDIM;
    for (int i = tid; i < 22 * HDIM; i += 512) comb[i] = hp[i];
    const float* hb = h_all + (size_t)(NPLAYER + b) * HDIM;
    for (int i = tid; i < HDIM; i += 512) comb[22 * HDIM + i] = hb[i];
    __syncthreads();

    for (int o = tid; o < 22 * 40; o += 512) {
        const int p = o / 40, row = o - p * 40;
        const float* wr = fc_w + (size_t)row * 2 * HDIM;
        const float* cp = comb + p * HDIM;
        const float* cb = comb + 22 * HDIM;
        float a0 = fc_b[row], a1 = 0.f, a2 = 0.f, a3 = 0.f;
        #pragma unroll
        for (int k = 0; k < HDIM; k += 4) {
            float4 wv = *(const float4*)(wr + k);
            float4 cv = *(const float4*)(cp + k);
            a0 = __builtin_fmaf(wv.x, cv.x, a0);
            a1 = __builtin_fmaf(wv.y, cv.y, a1);
            a2 = __builtin_fmaf(wv.z, cv.z, a2);
            a3 = __builtin_fmaf(wv.w, cv.w, a3);
        }
        #pragma unroll
        for (int k = 0; k < HDIM; k += 4) {
            float4 wv = *(const float4*)(wr + HDIM + k);
            float4 cv = *(const float4*)(cb + k);
            a0 = __builtin_fmaf(wv.x, cv.x, a0);
            a1 = __builtin_fmaf(wv.y, cv.y, a1);
            a2 = __builtin_fmaf(wv.z, cv.z, a2);
            a3 = __builtin_fmaf(wv.w, cv.w, a3);
        }
        out[(size_t)(b * 22 + p) * 40 + row] = (a0 + a1) + (a2 + a3);
    }
}

extern "C" void kernel_launch(void* const* d_in, const int* in_sizes, int n_in,
                              void* d_out, int out_size, void* d_ws, size_t ws_size,
                              hipStream_t stream) {
    const float* x_players = (const float*)d_in[0];
    const float* x_ball    = (const float*)d_in[1];
    const float* p_w_ih    = (const float*)d_in[2];
    const float* p_w_hh    = (const float*)d_in[3];
    const float* p_b_ih    = (const float*)d_in[4];
    const float* p_b_hh    = (const float*)d_in[5];
    const float* b_w_ih    = (const float*)d_in[6];
    const float* b_w_hh    = (const float*)d_in[7];
    const float* b_b_ih    = (const float*)d_in[8];
    const float* b_b_hh    = (const float*)d_in[9];
    const float* fc_w      = (const float*)d_in[10];
    const float* fc_b      = (const float*)d_in[11];

    float* h_all = (float*)d_ws;   // NSEQ * HDIM floats

    lstm_kernel<<<dim3(NBLK), dim3(512), 0, stream>>>(
        x_players, x_ball, p_w_ih, p_w_hh, p_b_ih, p_b_hh,
        b_w_ih, b_w_hh, b_b_ih, b_b_hh, h_all);

    fc_kernel<<<dim3(64), dim3(512), 0, stream>>>(
        h_all, fc_w, fc_b, (float*)d_out);
}

// Round 7
// 186.658 us; speedup vs baseline: 5.6494x; 1.1019x over previous
//
#include <hip/hip_runtime.h>

// TeamMovementModel R7: fp16 MFMA batched LSTM, 8 seqs/block, 184 blocks.
// vs R6 (115us lstm, 2156 cyc/step, VGPR=88 => weights live in AGPRs):
//  1. Pins use "+a" (AGPR) constraint: R6's "+v" pins forced per-step
//     v_accvgpr_read/write ping-pong (~128 movs/wave/step). "a" is free.
//  2. K-aug kt=5: W_ih@x + bias folded into MFMA via B rows 128..130
//     (removes 48 const VGPRs + their pins + 32 init FMAs + x ds_reads).
//  3. DPP row_ror:8 replaces 8 ds_swizzle shfl_xor (VALU, no lgkm waits).
//  4. 2-step unroll: compile-time buffer ping-pong.
//  5. fc reverted to R1 1408x64 form (R6's 64x512 fc cost ~90us of gap).

#define HDIM 128
#define TSTEPS 128
#define NPLAYER 1408
#define NSEQ 1472
#define NB 8
#define NBLK (NSEQ / NB)        // 184
#define NPBLK (NPLAYER / NB)    // 176
#define KT 5                    // k-tiles of 32 (K_aug = 160)
#define BSTR 168                // fp16 per B row (336 B stride)
#define XSTR 258                // floats per x col

typedef _Float16 f16x8 __attribute__((ext_vector_type(8)));
typedef _Float16 f16x2 __attribute__((ext_vector_type(2)));
typedef float    f32x4 __attribute__((ext_vector_type(4)));

__device__ __forceinline__ float rcp_fast(float x) { return __builtin_amdgcn_rcpf(x); }
__device__ __forceinline__ float sigmoid_f(float x) { return rcp_fast(1.0f + __expf(-x)); }
__device__ __forceinline__ float tanh_f(float x) {
    return 1.0f - 2.0f * rcp_fast(__expf(2.0f * x) + 1.0f);
}
// lane <-> lane^8 swap within 16-lane rows, on the VALU (no LDS pipe)
__device__ __forceinline__ float dpp_xor8(float x) {
    return __int_as_float(__builtin_amdgcn_update_dpp(
        __float_as_int(x), __float_as_int(x), 0x128 /*row_ror:8*/, 0xF, 0xF, false));
}

__global__ void __launch_bounds__(512)
__attribute__((amdgpu_waves_per_eu(2, 2)))
lstm_kernel(const float* __restrict__ x_players, const float* __restrict__ x_ball,
            const float* __restrict__ p_w_ih, const float* __restrict__ p_w_hh,
            const float* __restrict__ p_b_ih, const float* __restrict__ p_b_hh,
            const float* __restrict__ b_w_ih, const float* __restrict__ b_w_hh,
            const float* __restrict__ b_b_ih, const float* __restrict__ b_b_hh,
            float* __restrict__ h_all)
{
    const int tid  = threadIdx.x;
    const int blk  = blockIdx.x;          // 0..183; 176..183 ball
    const int w    = tid >> 6;            // wave -> h-rows [16w, 16w+16)
    const int lane = tid & 63;
    const int nn   = lane & 15;           // MFMA n (col)
    const int q    = lane >> 4;           // MFMA quad

    const bool ball = (blk >= NPBLK);
    const float* w_ih = ball ? b_w_ih : p_w_ih;
    const float* w_hh = ball ? b_w_hh : p_w_hh;
    const float* bih  = ball ? b_b_ih : p_b_ih;
    const float* bhh  = ball ? b_b_hh : p_b_hh;
    const float* xg   = ball ? (x_ball    + (size_t)(blk - NPBLK) * NB * TSTEPS * 2)
                             : (x_players + (size_t)blk * NB * TSTEPS * 2);

    __shared__ __align__(16) _Float16 b_sh[2][16 * BSTR];  // cols(rows of b_sh) 8..15 stay 0
    __shared__ __align__(16) float x_sh[NB * XSTR];

    for (int i = tid; i < NB * 256; i += 512)
        x_sh[(i >> 8) * XSTR + (i & 255)] = xg[i];
    for (int i = tid; i < 2 * 16 * BSTR / 2; i += 512)
        ((int*)b_sh)[i] = 0;

    // ---- A fragments: gate mi, row r = mi*128 + 16w + nn.
    // a[j] = A[m=lane&15][k = 32kt + 8q + j]; kt=4 aug: k=128:wi0 129:wi1 130:bias
    f16x8 afr[4][KT];
    #pragma unroll
    for (int mi = 0; mi < 4; ++mi) {
        const int r = mi * HDIM + w * 16 + nn;
        const float* wr = w_hh + (size_t)r * HDIM;
        #pragma unroll
        for (int kt = 0; kt < 4; ++kt) {
            const float* p = wr + kt * 32 + q * 8;
            f16x8 a8;
            #pragma unroll
            for (int j = 0; j < 8; ++j) a8[j] = (_Float16)p[j];
            afr[mi][kt] = a8;
        }
        f16x8 a8 = {};
        if (q == 0) {
            a8[0] = (_Float16)w_ih[2 * r];
            a8[1] = (_Float16)w_ih[2 * r + 1];
            a8[2] = (_Float16)(bih[r] + bhh[r]);
        }
        afr[mi][4] = a8;
    }

    const int colh   = nn & 7;                  // owned seq col
    const int rowoff = (nn < 8) ? 0 : 2;        // reg-split via DPP
    const int hrow   = w * 16 + 4 * q + rowoff; // first of 2 owned h-rows
    float c0 = 0.f, c1 = 0.f;

    __syncthreads();
    if (tid < NB) {   // x(0) into buf0; '1' aug col into both buffers
        _Float16* br0 = &b_sh[0][tid * BSTR];
        br0[128] = (_Float16)x_sh[tid * XSTR];
        br0[129] = (_Float16)x_sh[tid * XSTR + 1];
        br0[130] = (_Float16)1.0f;
        b_sh[1][tid * BSTR + 130] = (_Float16)1.0f;
    }
    __syncthreads();

    auto substep = [&](int s, const _Float16* bc, _Float16* bn) {
        // B frags. b[j] = B[k=32kt+8q+j][n=nn]
        f16x8 bfr[KT];
        #pragma unroll
        for (int kt = 0; kt < KT; ++kt)
            bfr[kt] = *(const f16x8*)(bc + nn * BSTR + kt * 32 + q * 8);

        f32x4 acc[4];
        #pragma unroll
        for (int mi = 0; mi < 4; ++mi) acc[mi] = (f32x4){0.f, 0.f, 0.f, 0.f};
        #pragma unroll
        for (int kt = 0; kt < KT; ++kt)
            #pragma unroll
            for (int mi = 0; mi < 4; ++mi)
                acc[mi] = __builtin_amdgcn_mfma_f32_16x16x32_f16(afr[mi][kt], bfr[kt], acc[mi], 0, 0, 0);

        // x(s+1) into next buffer (independent of the act chain; issues early)
        if (tid < NB && s + 1 < TSTEPS) {
            const float x0 = x_sh[tid * XSTR + 2 * (s + 1)];
            const float x1 = x_sh[tid * XSTR + 2 * (s + 1) + 1];
            *(f16x2*)&bn[tid * BSTR + 128] = (f16x2){(_Float16)x0, (_Float16)x1};
        }

        // reg-split swap on the VALU: lane nn<8 keeps regs {0,1} of col nn,
        // lane nn>=8 takes partner's regs {2,3} of col nn-8
        float u0[4], u1[4];
        #pragma unroll
        for (int mi = 0; mi < 4; ++mi) {
            const float r2 = dpp_xor8(acc[mi][2]);
            const float r3 = dpp_xor8(acc[mi][3]);
            u0[mi] = (nn < 8) ? acc[mi][0] : r2;
            u1[mi] = (nn < 8) ? acc[mi][1] : r3;
        }
        const float i0 = sigmoid_f(u0[0]), i1 = sigmoid_f(u1[0]);
        const float f0 = sigmoid_f(u0[1]), f1 = sigmoid_f(u1[1]);
        const float g0 = tanh_f(u0[2]),    g1 = tanh_f(u1[2]);
        const float o0 = sigmoid_f(u0[3]), o1 = sigmoid_f(u1[3]);
        c0 = __builtin_fmaf(f0, c0, i0 * g0);
        c1 = __builtin_fmaf(f1, c1, i1 * g1);
        const float h0 = o0 * tanh_f(c0);
        const float h1 = o1 * tanh_f(c1);

        *(f16x2*)&bn[colh * BSTR + hrow] = (f16x2){(_Float16)h0, (_Float16)h1};

        if (s == TSTEPS - 1) {
            float* hp = h_all + (size_t)(blk * NB + colh) * HDIM + hrow;
            hp[0] = h0; hp[1] = h1;
        }
        __syncthreads();
    };

    _Float16* b0 = &b_sh[0][0];
    _Float16* b1 = &b_sh[1][0];
    #pragma unroll 1
    for (int it = 0; it < TSTEPS / 2; ++it) {
        substep(2 * it,     b0, b1);
        substep(2 * it + 1, b1, b0);
        // loop-carried AGPR pins: block rematerialization, zero cost if the
        // fragments live in AGPRs (MFMA reads A from AGPR on gfx950)
        asm volatile("" :
            "+a"(afr[0][0]), "+a"(afr[0][1]), "+a"(afr[0][2]), "+a"(afr[0][3]), "+a"(afr[0][4]),
            "+a"(afr[1][0]), "+a"(afr[1][1]), "+a"(afr[1][2]), "+a"(afr[1][3]), "+a"(afr[1][4]),
            "+a"(afr[2][0]), "+a"(afr[2][1]), "+a"(afr[2][2]), "+a"(afr[2][3]), "+a"(afr[2][4]),
            "+a"(afr[3][0]), "+a"(afr[3][1]), "+a"(afr[3][2]), "+a"(afr[3][3]), "+a"(afr[3][4]));
    }
}

__global__ void __launch_bounds__(64)
fc_kernel(const float* __restrict__ h_all, const float* __restrict__ fc_w,
          const float* __restrict__ fc_b, float* __restrict__ out)
{
    const int blk = blockIdx.x;        // 0..1407 == b*22 + p
    const int b   = blk / 22;
    const int t   = threadIdx.x;       // 0..63

    __shared__ __align__(16) float comb[2 * HDIM];
    for (int i = t; i < HDIM; i += 64) {
        comb[i]        = h_all[(size_t)blk * HDIM + i];
        comb[HDIM + i] = h_all[(size_t)(NPLAYER + b) * HDIM + i];
    }
    __syncthreads();

    if (t < 40) {
        const float* wr = fc_w + (size_t)t * 2 * HDIM;
        float acc = fc_b[t];
        float a1 = 0.0f, a2 = 0.0f, a3 = 0.0f;
        #pragma unroll
        for (int k = 0; k < 2 * HDIM; k += 4) {
            float4 wv = *(const float4*)(wr + k);
            float4 cv = *(const float4*)(comb + k);
            acc = __builtin_fmaf(wv.x, cv.x, acc);
            a1  = __builtin_fmaf(wv.y, cv.y, a1);
            a2  = __builtin_fmaf(wv.z, cv.z, a2);
            a3  = __builtin_fmaf(wv.w, cv.w, a3);
        }
        out[(size_t)blk * 40 + t] = acc + (a1 + a2) + a3;
    }
}

extern "C" void kernel_launch(void* const* d_in, const int* in_sizes, int n_in,
                              void* d_out, int out_size, void* d_ws, size_t ws_size,
                              hipStream_t stream) {
    const float* x_players = (const float*)d_in[0];
    const float* x_ball    = (const float*)d_in[1];
    const float* p_w_ih    = (const float*)d_in[2];
    const float* p_w_hh    = (const float*)d_in[3];
    const float* p_b_ih    = (const float*)d_in[4];
    const float* p_b_hh    = (const float*)d_in[5];
    const float* b_w_ih    = (const float*)d_in[6];
    const float* b_w_hh    = (const float*)d_in[7];
    const float* b_b_ih    = (const float*)d_in[8];
    const float* b_b_hh    = (const float*)d_in[9];
    const float* fc_w      = (const float*)d_in[10];
    const float* fc_b      = (const float*)d_in[11];

    float* h_all = (float*)d_ws;   // NSEQ * HDIM floats

    lstm_kernel<<<dim3(NBLK), dim3(512), 0, stream>>>(
        x_players, x_ball, p_w_ih, p_w_hh, p_b_ih, p_b_hh,
        b_w_ih, b_w_hh, b_b_ih, b_b_hh, h_all);

    fc_kernel<<<dim3(NPLAYER), dim3(64), 0, stream>>>(
        h_all, fc_w, fc_b, (float*)d_out);
}

// Round 8
// 185.386 us; speedup vs baseline: 5.6882x; 1.0069x over previous
//
#include <hip/hip_runtime.h>

// TeamMovementModel R8: fp16 MFMA batched LSTM, 8 seqs/block, 184 blocks.
// Model from R7 counters: step = lockstep phase SUM (LDS 340 + MFMA 460 +
// VALU 810 + sync ≈ 2112 cyc). This round shrinks the terms:
//  1. Exec-masked B reads: lanes nn>=8 hold constant-zero frags in regs
//     (B cols 8..15 are structurally zero) -> LDS read traffic halves.
//  2. __builtin_amdgcn_exp2f activations (native v_exp, no log2e mul).
//  3. Step-127 peel: no per-step branch, no final barrier, h stored from regs.
//  4. fc: 176 blocks x 256 thr (8 players each).

#define HDIM 128
#define TSTEPS 128
#define NPLAYER 1408
#define NSEQ 1472
#define NB 8
#define NBLK (NSEQ / NB)        // 184
#define NPBLK (NPLAYER / NB)    // 176
#define KT 5                    // k-tiles of 32 (K_aug = 160)
#define BSTR 168                // fp16 per B row (336 B stride)
#define XSTR 258                // floats per x col

typedef _Float16 f16x8 __attribute__((ext_vector_type(8)));
typedef _Float16 f16x2 __attribute__((ext_vector_type(2)));
typedef float    f32x4 __attribute__((ext_vector_type(4)));

#define LOG2E 1.44269504f

__device__ __forceinline__ float rcp_fast(float x) { return __builtin_amdgcn_rcpf(x); }
__device__ __forceinline__ float sigmoid_f(float x) {
    // 1/(1+2^(-x*log2e)) : one v_exp + one v_rcp
    return rcp_fast(1.0f + __builtin_amdgcn_exp2f(-LOG2E * x));
}
__device__ __forceinline__ float tanh_f(float x) {
    // 1 - 2/(2^(2x*log2e)+1); stable both ends (rcp(inf)=0)
    return 1.0f - 2.0f * rcp_fast(__builtin_amdgcn_exp2f(2.0f * LOG2E * x) + 1.0f);
}
// lane <-> lane^8 swap within 16-lane rows, on the VALU (no LDS pipe)
__device__ __forceinline__ float dpp_xor8(float x) {
    return __int_as_float(__builtin_amdgcn_update_dpp(
        __float_as_int(x), __float_as_int(x), 0x128 /*row_ror:8*/, 0xF, 0xF, false));
}

__global__ void __launch_bounds__(512)
__attribute__((amdgpu_waves_per_eu(2, 2)))
lstm_kernel(const float* __restrict__ x_players, const float* __restrict__ x_ball,
            const float* __restrict__ p_w_ih, const float* __restrict__ p_w_hh,
            const float* __restrict__ p_b_ih, const float* __restrict__ p_b_hh,
            const float* __restrict__ b_w_ih, const float* __restrict__ b_w_hh,
            const float* __restrict__ b_b_ih, const float* __restrict__ b_b_hh,
            float* __restrict__ h_all)
{
    const int tid  = threadIdx.x;
    const int blk  = blockIdx.x;          // 0..183; 176..183 ball
    const int w    = tid >> 6;            // wave -> h-rows [16w, 16w+16)
    const int lane = tid & 63;
    const int nn   = lane & 15;           // MFMA n (col)
    const int q    = lane >> 4;           // MFMA quad

    const bool ball = (blk >= NPBLK);
    const float* w_ih = ball ? b_w_ih : p_w_ih;
    const float* w_hh = ball ? b_w_hh : p_w_hh;
    const float* bih  = ball ? b_b_ih : p_b_ih;
    const float* bhh  = ball ? b_b_hh : p_b_hh;
    const float* xg   = ball ? (x_ball    + (size_t)(blk - NPBLK) * NB * TSTEPS * 2)
                             : (x_players + (size_t)blk * NB * TSTEPS * 2);

    // B operand: only 8 rows now (cols 8..15 are constant-zero REGISTER frags)
    __shared__ __align__(16) _Float16 b_sh[2][NB * BSTR];
    __shared__ __align__(16) float x_sh[NB * XSTR];

    for (int i = tid; i < NB * 256; i += 512)
        x_sh[(i >> 8) * XSTR + (i & 255)] = xg[i];
    for (int i = tid; i < 2 * NB * BSTR / 2; i += 512)
        ((int*)b_sh)[i] = 0;

    // ---- A fragments: gate mi, row r = mi*128 + 16w + nn.
    // a[j] = A[m=lane&15][k = 32kt + 8q + j]; kt=4 aug: k=128:wi0 129:wi1 130:bias
    f16x8 afr[4][KT];
    #pragma unroll
    for (int mi = 0; mi < 4; ++mi) {
        const int r = mi * HDIM + w * 16 + nn;
        const float* wr = w_hh + (size_t)r * HDIM;
        #pragma unroll
        for (int kt = 0; kt < 4; ++kt) {
            const float* p = wr + kt * 32 + q * 8;
            f16x8 a8;
            #pragma unroll
            for (int j = 0; j < 8; ++j) a8[j] = (_Float16)p[j];
            afr[mi][kt] = a8;
        }
        f16x8 a8 = {};
        if (q == 0) {
            a8[0] = (_Float16)w_ih[2 * r];
            a8[1] = (_Float16)w_ih[2 * r + 1];
            a8[2] = (_Float16)(bih[r] + bhh[r]);
        }
        afr[mi][4] = a8;
    }

    const int colh   = nn & 7;                  // owned seq col
    const int rowoff = (nn < 8) ? 0 : 2;        // reg-split via DPP
    const int hrow   = w * 16 + 4 * q + rowoff; // first of 2 owned h-rows
    float c0 = 0.f, c1 = 0.f;
    float h0 = 0.f, h1 = 0.f;

    __syncthreads();
    if (tid < NB) {   // x(0) into buf0; '1' aug col into both buffers
        _Float16* br0 = &b_sh[0][tid * BSTR];
        br0[128] = (_Float16)x_sh[tid * XSTR];
        br0[129] = (_Float16)x_sh[tid * XSTR + 1];
        br0[130] = (_Float16)1.0f;
        b_sh[1][tid * BSTR + 130] = (_Float16)1.0f;
    }
    __syncthreads();

    // zero-frags for lanes nn>=8 persist across the whole loop
    f16x8 bfr[KT] = {};

    auto substep = [&](int s, const _Float16* bc, _Float16* bn, bool last) {
        // masked B read: only 32 lanes/wave touch LDS (cols 8..15 stay zero regs)
        if (nn < 8) {
            #pragma unroll
            for (int kt = 0; kt < KT; ++kt)
                bfr[kt] = *(const f16x8*)(bc + nn * BSTR + kt * 32 + q * 8);
        }

        f32x4 acc[4];
        #pragma unroll
        for (int mi = 0; mi < 4; ++mi) acc[mi] = (f32x4){0.f, 0.f, 0.f, 0.f};
        #pragma unroll
        for (int kt = 0; kt < KT; ++kt)
            #pragma unroll
            for (int mi = 0; mi < 4; ++mi)
                acc[mi] = __builtin_amdgcn_mfma_f32_16x16x32_f16(afr[mi][kt], bfr[kt], acc[mi], 0, 0, 0);

        // x(s+1) into next buffer (independent of the act chain)
        if (!last && tid < NB) {
            const float x0 = x_sh[tid * XSTR + 2 * (s + 1)];
            const float x1 = x_sh[tid * XSTR + 2 * (s + 1) + 1];
            *(f16x2*)&bn[tid * BSTR + 128] = (f16x2){(_Float16)x0, (_Float16)x1};
        }

        // reg-split swap: lane nn<8 keeps regs {0,1} of col nn,
        // lane nn>=8 takes partner's regs {2,3} of col nn-8
        float u0[4], u1[4];
        #pragma unroll
        for (int mi = 0; mi < 4; ++mi) {
            const float r2 = dpp_xor8(acc[mi][2]);
            const float r3 = dpp_xor8(acc[mi][3]);
            u0[mi] = (nn < 8) ? acc[mi][0] : r2;
            u1[mi] = (nn < 8) ? acc[mi][1] : r3;
        }
        const float i0 = sigmoid_f(u0[0]), i1 = sigmoid_f(u1[0]);
        const float f0 = sigmoid_f(u0[1]), f1 = sigmoid_f(u1[1]);
        const float g0 = tanh_f(u0[2]),    g1 = tanh_f(u1[2]);
        const float o0 = sigmoid_f(u0[3]), o1 = sigmoid_f(u1[3]);
        c0 = __builtin_fmaf(f0, c0, i0 * g0);
        c1 = __builtin_fmaf(f1, c1, i1 * g1);
        h0 = o0 * tanh_f(c0);
        h1 = o1 * tanh_f(c1);

        if (!last) {
            *(f16x2*)&bn[colh * BSTR + hrow] = (f16x2){(_Float16)h0, (_Float16)h1};
            __syncthreads();
        }
    };

    _Float16* b0 = &b_sh[0][0];
    _Float16* b1 = &b_sh[1][0];
    #pragma unroll 1
    for (int it = 0; it < TSTEPS / 2 - 1; ++it) {   // steps 0..125
        substep(2 * it,     b0, b1, false);
        substep(2 * it + 1, b1, b0, false);
        // loop-carried AGPR pins: block rematerialization (R1..R5 failure mode)
        asm volatile("" :
            "+a"(afr[0][0]), "+a"(afr[0][1]), "+a"(afr[0][2]), "+a"(afr[0][3]), "+a"(afr[0][4]),
            "+a"(afr[1][0]), "+a"(afr[1][1]), "+a"(afr[1][2]), "+a"(afr[1][3]), "+a"(afr[1][4]),
            "+a"(afr[2][0]), "+a"(afr[2][1]), "+a"(afr[2][2]), "+a"(afr[2][3]), "+a"(afr[2][4]),
            "+a"(afr[3][0]), "+a"(afr[3][1]), "+a"(afr[3][2]), "+a"(afr[3][3]), "+a"(afr[3][4]));
    }
    substep(126, b0, b1, false);
    substep(127, b1, b0, true);    // peeled: no h-write, no barrier

    float* hp = h_all + (size_t)(blk * NB + colh) * HDIM + hrow;
    hp[0] = h0; hp[1] = h1;
}

// FC: 176 blocks x 256 thr; block = 8 players. comb[p] = [player_h ; ball_h].
__global__ void __launch_bounds__(256)
fc_kernel(const float* __restrict__ h_all, const float* __restrict__ fc_w,
          const float* __restrict__ fc_b, float* __restrict__ out)
{
    const int blk = blockIdx.x;        // players [8*blk, 8*blk+8)
    const int tid = threadIdx.x;

    __shared__ __align__(16) float comb[8][2 * HDIM];
    for (int i = tid; i < 8 * HDIM; i += 256) {
        const int p = i >> 7, off = i & 127;
        const int gp = 8 * blk + p;
        comb[p][off]        = h_all[(size_t)gp * HDIM + off];
        comb[p][HDIM + off] = h_all[(size_t)(NPLAYER + gp / 22) * HDIM + off];
    }
    __syncthreads();

    for (int o = tid; o < 8 * 40; o += 256) {
        const int p = o / 40, row = o - p * 40;
        const float* wr = fc_w + (size_t)row * 2 * HDIM;
        const float* cp = &comb[p][0];
        float a0 = fc_b[row], a1 = 0.f, a2 = 0.f, a3 = 0.f;
        #pragma unroll
        for (int k = 0; k < 2 * HDIM; k += 4) {
            float4 wv = *(const float4*)(wr + k);
            float4 cv = *(const float4*)(cp + k);
            a0 = __builtin_fmaf(wv.x, cv.x, a0);
            a1 = __builtin_fmaf(wv.y, cv.y, a1);
            a2 = __builtin_fmaf(wv.z, cv.z, a2);
            a3 = __builtin_fmaf(wv.w, cv.w, a3);
        }
        out[(size_t)(8 * blk + p) * 40 + row] = (a0 + a1) + (a2 + a3);
    }
}

extern "C" void kernel_launch(void* const* d_in, const int* in_sizes, int n_in,
                              void* d_out, int out_size, void* d_ws, size_t ws_size,
                              hipStream_t stream) {
    const float* x_players = (const float*)d_in[0];
    const float* x_ball    = (const float*)d_in[1];
    const float* p_w_ih    = (const float*)d_in[2];
    const float* p_w_hh    = (const float*)d_in[3];
    const float* p_b_ih    = (const float*)d_in[4];
    const float* p_b_hh    = (const float*)d_in[5];
    const float* b_w_ih    = (const float*)d_in[6];
    const float* b_w_hh    = (const float*)d_in[7];
    const float* b_b_ih    = (const float*)d_in[8];
    const float* b_b_hh    = (const float*)d_in[9];
    const float* fc_w      = (const float*)d_in[10];
    const float* fc_b      = (const float*)d_in[11];

    float* h_all = (float*)d_ws;   // NSEQ * HDIM floats

    lstm_kernel<<<dim3(NBLK), dim3(512), 0, stream>>>(
        x_players, x_ball, p_w_ih, p_w_hh, p_b_ih, p_b_hh,
        b_w_ih, b_w_hh, b_b_ih, b_b_hh, h_all);

    fc_kernel<<<dim3(NPBLK), dim3(256), 0, stream>>>(
        h_all, fc_w, fc_b, (float*)d_out);
}